// Round 2
// baseline (541.849 us; speedup 1.0000x reference)
//
#include <hip/hip_runtime.h>

typedef unsigned short ushort_t;
typedef __attribute__((ext_vector_type(8))) __bf16 bf16x8;
typedef __attribute__((ext_vector_type(4))) float f32x4;

#define K_DIM 32768
#define M_DIM 1024
#define NBLK 256

__device__ __forceinline__ ushort_t f2bf_rne(float f) {
  unsigned int u = __float_as_uint(f);
  unsigned int r = (u + 0x7fffu + ((u >> 16) & 1u)) >> 16;
  return (ushort_t)r;
}

__device__ __forceinline__ void async16(const ushort_t* g, ushort_t* l) {
  __builtin_amdgcn_global_load_lds(
      (const __attribute__((address_space(1))) void*)g,
      (__attribute__((address_space(3))) void*)l,
      16, 0, 0);
}

// agent-scope (device) coherent accessors: bypass non-coherent L1/L2 so
// cross-block data never needs cache-flush fences.
__device__ __forceinline__ float aload(const float* p) {
  return __hip_atomic_load(p, __ATOMIC_RELAXED, __HIP_MEMORY_SCOPE_AGENT);
}
__device__ __forceinline__ void astore(float* p, float v) {
  __hip_atomic_store(p, v, __ATOMIC_RELAXED, __HIP_MEMORY_SCOPE_AGENT);
}

// grid barrier: distinct counter per barrier (zeroed by launch-start memset).
// grid=256 blocks of 256 thr, tiny LDS -> always co-resident on 256 CUs.
__device__ __forceinline__ void gbar(unsigned* bar, int idx) {
  __syncthreads();
  if (threadIdx.x == 0) {
    __hip_atomic_fetch_add(&bar[idx], 1u, __ATOMIC_RELEASE,
                           __HIP_MEMORY_SCOPE_AGENT);
    while (__hip_atomic_load(&bar[idx], __ATOMIC_ACQUIRE,
                             __HIP_MEMORY_SCOPE_AGENT) < (unsigned)NBLK)
      __builtin_amdgcn_s_sleep(2);
  }
  __syncthreads();
}

// ---------------------------------------------------------------------------
// Kernel A (unchanged from R1): pass over fp32 A [32768 x 1024]:
//   ss[j] = sum_i A[i][j]^2 ; c[j] = sum_i A[i][j]*x[i] ; AhiT = bf16(A)^T
// ---------------------------------------------------------------------------
__global__ __launch_bounds__(256) void k_stats_split(
    const float* __restrict__ A, const float* __restrict__ x,
    ushort_t* __restrict__ AhiT, float* __restrict__ ss, float* __restrict__ c) {
  __shared__ float xs[64];
  __shared__ ushort_t hi[256 * 65];
  __shared__ float red_ss[4][256];
  __shared__ float red_c[4][256];
  const int t = threadIdx.x;
  const int i0 = blockIdx.x * 64;
  const int j0 = blockIdx.y * 256;
  if (t < 64) xs[t] = x[i0 + t];
  __syncthreads();
  const int jj = (t & 63) * 4;
  const int iw = t >> 6;
  float s0 = 0.f, s1 = 0.f, s2 = 0.f, s3 = 0.f;
  float c0 = 0.f, c1 = 0.f, c2 = 0.f, c3 = 0.f;
  for (int p = 0; p < 16; ++p) {
    const int ii = iw + p * 4;
    const float4 w = *(const float4*)(A + (size_t)(i0 + ii) * M_DIM + j0 + jj);
    const float xv = xs[ii];
    s0 += w.x * w.x; s1 += w.y * w.y; s2 += w.z * w.z; s3 += w.w * w.w;
    c0 += w.x * xv;  c1 += w.y * xv;  c2 += w.z * xv;  c3 += w.w * xv;
    hi[(jj + 0) * 65 + ii] = f2bf_rne(w.x);
    hi[(jj + 1) * 65 + ii] = f2bf_rne(w.y);
    hi[(jj + 2) * 65 + ii] = f2bf_rne(w.z);
    hi[(jj + 3) * 65 + ii] = f2bf_rne(w.w);
  }
  red_ss[iw][jj + 0] = s0; red_ss[iw][jj + 1] = s1;
  red_ss[iw][jj + 2] = s2; red_ss[iw][jj + 3] = s3;
  red_c[iw][jj + 0] = c0;  red_c[iw][jj + 1] = c1;
  red_c[iw][jj + 2] = c2;  red_c[iw][jj + 3] = c3;
  __syncthreads();
  {
    const float S = red_ss[0][t] + red_ss[1][t] + red_ss[2][t] + red_ss[3][t];
    const float C = red_c[0][t] + red_c[1][t] + red_c[2][t] + red_c[3][t];
    atomicAdd(&ss[j0 + t], S);
    atomicAdd(&c[j0 + t], C);
  }
  for (int q = 0; q < 16; ++q) {
    const int lin = q * 256 + t;
    const int J = lin >> 4;
    const int I = (lin & 15) * 4;
    ushort4 val;
    val.x = hi[J * 65 + I + 0];
    val.y = hi[J * 65 + I + 1];
    val.z = hi[J * 65 + I + 2];
    val.w = hi[J * 65 + I + 3];
    *(ushort4*)(AhiT + (size_t)(j0 + J) * K_DIM + i0 + I) = val;
  }
}

// ---------------------------------------------------------------------------
// Kernel B: SYRK, lower-triangle 128x128 tiles only (36), grid (36, 32
// K-splits) = 1152 blocks. XOR-swizzled LDS (conflict-free fragment reads);
// diagonal tiles stage a single panel. fp32 atomicAdd into zeroed G.
// ---------------------------------------------------------------------------
__global__ __launch_bounds__(256) void k_syrk(const ushort_t* __restrict__ AT,
                                              float* __restrict__ G) {
  __shared__ __align__(16) ushort_t shI[128 * 32];
  __shared__ __align__(16) ushort_t shJ[128 * 32];
  const int t = threadIdx.x;
  const int lane = t & 63;
  const int w = t >> 6;
  // tile -> (ti, tj), ti >= tj
  int ti = 0, tt = blockIdx.x;
  while (tt >= ti + 1) { tt -= ti + 1; ++ti; }
  const int tj = tt;
  const int I0 = ti * 128, J0 = tj * 128;
  const bool diag = (ti == tj);
  const int ks = blockIdx.y;
  const int wr = (w >> 1) * 64;
  const int wc = (w & 1) * 64;
  const int fm = lane & 15;
  const int fq = lane >> 4;
  f32x4 acc[4][4] = {};
  // staging slots: slot s -> (row = s>>2, part = s&3); stored global k-part is
  // part ^ ((row>>1)&3) so fragment reads spread over all 8 bank-quads.
  const int sa = t, sb = t + 256;
  const int ra = sa >> 2, pa = sa & 3;
  const int rb = sb >> 2, pb = sb & 3;
  const int qa = pa ^ ((ra >> 1) & 3);
  const int qb = pb ^ ((rb >> 1) & 3);
  size_t k0 = (size_t)ks * 1024;
  for (int kt = 0; kt < 32; ++kt, k0 += 32) {
    async16(AT + ((size_t)(I0 + ra) << 15) + k0 + qa * 8, shI + sa * 8);
    async16(AT + ((size_t)(I0 + rb) << 15) + k0 + qb * 8, shI + sb * 8);
    if (!diag) {
      async16(AT + ((size_t)(J0 + ra) << 15) + k0 + qa * 8, shJ + sa * 8);
      async16(AT + ((size_t)(J0 + rb) << 15) + k0 + qb * 8, shJ + sb * 8);
    }
    __syncthreads();
    const ushort_t* shB = diag ? shI : shJ;
    bf16x8 af[4], bfr[4];
#pragma unroll
    for (int i = 0; i < 4; ++i) {
      const int rI = wr + i * 16 + fm;
      af[i]  = *(const bf16x8*)(shI + (rI * 4 + (fq ^ ((rI >> 1) & 3))) * 8);
      const int rJ = wc + i * 16 + fm;
      bfr[i] = *(const bf16x8*)(shB + (rJ * 4 + (fq ^ ((rJ >> 1) & 3))) * 8);
    }
#pragma unroll
    for (int i = 0; i < 4; ++i)
#pragma unroll
      for (int j = 0; j < 4; ++j)
        acc[i][j] = __builtin_amdgcn_mfma_f32_16x16x32_bf16(af[i], bfr[j],
                                                            acc[i][j], 0, 0, 0);
    __syncthreads();
  }
  // C/D layout (m89): col = lane&15, row = (lane>>4)*4 + reg
#pragma unroll
  for (int i = 0; i < 4; ++i)
#pragma unroll
    for (int j = 0; j < 4; ++j)
#pragma unroll
      for (int rg = 0; rg < 4; ++rg) {
        const int row = I0 + wr + i * 16 + fq * 4 + rg;
        const int col = J0 + wc + j * 16 + fm;
        atomicAdd(&G[row * M_DIM + col], acc[i][j][rg]);
      }
}

// ---------------------------------------------------------------------------
// Kernel C: fused solve. Phases (grid-barriered):
//  T) mirror lower->upper G (120 strictly-lower 64x64 tiles, via LDS transpose)
//  1) init d0 = c/theta; 7 Chebyshev iters on G x1 = c
//  2) refinement residual v = A^T(A x1) with fp32 A, chunked so A is read once
//  3) 5 Chebyshev iters on G x2 = c - v
//  4) block 0: out = sqrt(ss)*(x1+x2), threshold at std(ddof=1)
// x/r held in lane-0 registers; only d/x published (agent scope) per iter.
// ---------------------------------------------------------------------------
__global__ __launch_bounds__(256) void k_solve(
    const float* __restrict__ A, float* __restrict__ G,
    const float* __restrict__ ss, const float* __restrict__ c,
    float* __restrict__ v, float* __restrict__ x1g, float* __restrict__ x2g,
    float* da, float* db, unsigned* __restrict__ bar,
    float* __restrict__ out) {
  __shared__ float smem[64 * 65];
  __shared__ float thr_s;
  const int t = threadIdx.x;
  const int b = blockIdx.x;
  const int lane = t & 63;
  const int w = t >> 6;

  // ---- Phase T: symmetrize (write-through agent stores; no fence needed)
  if (b < 120) {
    int bi = 1, rem = b;
    while (rem >= bi) { rem -= bi; ++bi; }
    const int bj = rem;                       // bi in 1..15, bj < bi
    const int sr = t >> 2, sc0 = (t & 3) * 16;
    const float* srow = G + (size_t)(bi * 64 + sr) * M_DIM + bj * 64 + sc0;
#pragma unroll
    for (int q = 0; q < 4; ++q) {
      const float4 sv = *(const float4*)(srow + q * 4);
      smem[(sc0 + q * 4 + 0) * 65 + sr] = sv.x;
      smem[(sc0 + q * 4 + 1) * 65 + sr] = sv.y;
      smem[(sc0 + q * 4 + 2) * 65 + sr] = sv.z;
      smem[(sc0 + q * 4 + 3) * 65 + sr] = sv.w;
    }
    __syncthreads();
    const int dr = t >> 2, dc0 = (t & 3) * 16;
    float* drow = G + (size_t)(bj * 64 + dr) * M_DIM + bi * 64;
#pragma unroll
    for (int q = 0; q < 16; ++q)
      astore(drow + dc0 + q, smem[dr * 65 + dc0 + q]);
  }

  // ---- init solve 1
  const int row = b * 4 + w;
  const float* grow = G + (size_t)row * M_DIM;
  const float invTheta = 1.0f / 34406.4f;     // theta = 1.05*32768
  float x_own = 0.f, r_own = 0.f, d_own = 0.f;
  if (lane == 0) {
    r_own = c[row];
    d_own = r_own * invTheta;
    astore(&da[row], d_own);
  }
  gbar(bar, 0);

  auto cheb_iter = [&](const float* din, float* dout, float beta, float gamma,
                       float* xg) {
    float p = 0.f;
#pragma unroll
    for (int s = 0; s < 16; ++s) {
      const int j = lane + 64 * s;
      p += grow[j] * aload(din + j);
    }
#pragma unroll
    for (int off = 32; off > 0; off >>= 1) p += __shfl_down(p, off);
    if (lane == 0) {
      x_own += d_own;
      r_own -= p;
      d_own = beta * d_own + gamma * r_own;
      astore(dout + row, d_own);
      astore(xg + row, x_own);
    }
  };

  // sigma = 2.1, delta = 16384
  double rho = 1.0 / 2.1;
  {
    const float* din = da; float* dout = db;
    for (int k = 0; k < 7; ++k) {
      const double rho_n = 1.0 / (4.2 - rho);
      cheb_iter(din, dout, (float)(rho_n * rho),
                (float)(2.0 * rho_n / 16384.0), x1g);
      gbar(bar, 1 + k);
      float* tmp = (float*)din; din = dout; dout = tmp;
      rho = rho_n;
    }
  }

  // ---- refinement: v = A^T (A x1), A read once (chunks stay L2-hot)
  float* yls = smem;          // 1024
  float* us16 = smem + 1024;  // 16
  for (int i = t; i < 1024; i += 256) yls[i] = aload(&x1g[i]);
  __syncthreads();
  float va0 = 0.f, va1 = 0.f, va2 = 0.f, va3 = 0.f;
  const int j4 = t * 4;
  const size_t ib = (size_t)b * 128;
  for (int ch = 0; ch < 8; ++ch) {
    const float* a0 = A + (ib + ch * 16 + w * 4) * M_DIM;
    float p0 = 0.f, p1 = 0.f, p2 = 0.f, p3 = 0.f;
#pragma unroll
    for (int s = 0; s < 16; ++s) {
      const int j = lane + 64 * s;
      const float yv = yls[j];
      p0 += a0[j] * yv;
      p1 += a0[j + 1024] * yv;
      p2 += a0[j + 2048] * yv;
      p3 += a0[j + 3072] * yv;
    }
#pragma unroll
    for (int off = 32; off > 0; off >>= 1) {
      p0 += __shfl_down(p0, off); p1 += __shfl_down(p1, off);
      p2 += __shfl_down(p2, off); p3 += __shfl_down(p3, off);
    }
    if (lane == 0) {
      us16[w * 4 + 0] = p0; us16[w * 4 + 1] = p1;
      us16[w * 4 + 2] = p2; us16[w * 4 + 3] = p3;
    }
    __syncthreads();
#pragma unroll
    for (int i = 0; i < 16; ++i) {
      const float uv = us16[i];
      const float4 av = *(const float4*)(A + (ib + ch * 16 + i) * M_DIM + j4);
      va0 += av.x * uv; va1 += av.y * uv; va2 += av.z * uv; va3 += av.w * uv;
    }
    __syncthreads();
  }
  atomicAdd(&v[j4 + 0], va0); atomicAdd(&v[j4 + 1], va1);
  atomicAdd(&v[j4 + 2], va2); atomicAdd(&v[j4 + 3], va3);
  gbar(bar, 8);

  // ---- init solve 2
  if (lane == 0) {
    r_own = c[row] - aload(&v[row]);
    x_own = 0.f;
    d_own = r_own * invTheta;
    astore(&da[row], d_own);
  }
  gbar(bar, 9);
  rho = 1.0 / 2.1;
  {
    const float* din = da; float* dout = db;
    for (int k = 0; k < 5; ++k) {
      const double rho_n = 1.0 / (4.2 - rho);
      cheb_iter(din, dout, (float)(rho_n * rho),
                (float)(2.0 * rho_n / 16384.0), x2g);
      gbar(bar, 10 + k);
      float* tmp = (float*)din; din = dout; dout = tmp;
      rho = rho_n;
    }
  }

  // ---- epilogue (block 0)
  if (b == 0) {
    float o0 = sqrtf(ss[j4 + 0]) * (aload(&x1g[j4 + 0]) + aload(&x2g[j4 + 0]));
    float o1 = sqrtf(ss[j4 + 1]) * (aload(&x1g[j4 + 1]) + aload(&x2g[j4 + 1]));
    float o2 = sqrtf(ss[j4 + 2]) * (aload(&x1g[j4 + 2]) + aload(&x2g[j4 + 2]));
    float o3 = sqrtf(ss[j4 + 3]) * (aload(&x1g[j4 + 3]) + aload(&x2g[j4 + 3]));
    float* red1 = smem;
    float* red2 = smem + 256;
    red1[t] = o0 + o1 + o2 + o3;
    red2[t] = o0 * o0 + o1 * o1 + o2 * o2 + o3 * o3;
    __syncthreads();
    for (int s = 128; s > 0; s >>= 1) {
      if (t < s) { red1[t] += red1[t + s]; red2[t] += red2[t + s]; }
      __syncthreads();
    }
    if (t == 0) {
      const float S1 = red1[0], S2 = red2[0];
      const float mean = S1 * (1.0f / 1024.0f);
      const float var = (S2 - 1024.0f * mean * mean) * (1.0f / 1023.0f);
      thr_s = sqrtf(fmaxf(var, 0.f));
    }
    __syncthreads();
    const float thr = thr_s;
    out[j4 + 0] = (o0 > thr) ? o0 : 0.f;
    out[j4 + 1] = (o1 > thr) ? o1 : 0.f;
    out[j4 + 2] = (o2 > thr) ? o2 : 0.f;
    out[j4 + 3] = (o3 > thr) ? o3 : 0.f;
  }
}

extern "C" void kernel_launch(void* const* d_in, const int* in_sizes, int n_in,
                              void* d_out, int out_size, void* d_ws, size_t ws_size,
                              hipStream_t stream) {
  (void)in_sizes; (void)n_in; (void)out_size; (void)ws_size;
  const float* x = (const float*)d_in[0];
  const float* A = (const float*)d_in[1];
  float* out = (float*)d_out;
  float* ws = (float*)d_ws;

  // ws (floats): G(1M) | ss | c | v | x1g | x2g | da | db | bar(64 u32) | AhiT
  float* G   = ws;
  float* ss  = ws + (1u << 20);
  float* c   = ss + 1024;
  float* v   = c + 1024;
  float* x1g = v + 1024;
  float* x2g = x1g + 1024;
  float* da  = x2g + 1024;
  float* db  = da + 1024;
  unsigned* bar = (unsigned*)(db + 1024);
  ushort_t* AhiT = (ushort_t*)(bar + 64);   // byte offset 4223232 (16B aligned)

  // zero G + accumulators + barrier counters
  hipMemsetAsync(ws, 0, (size_t)4223232, stream);

  k_stats_split<<<dim3(512, 4), 256, 0, stream>>>(A, x, AhiT, ss, c);
  k_syrk<<<dim3(36, 32), 256, 0, stream>>>(AhiT, G);
  k_solve<<<NBLK, 256, 0, stream>>>(A, G, ss, c, v, x1g, x2g, da, db, bar, out);
}